// Round 4
// baseline (592.150 us; speedup 1.0000x reference)
//
#include <hip/hip_runtime.h>
#include <stdint.h>

typedef unsigned short u16;
typedef unsigned int u32;
typedef unsigned long long u64;

typedef __attribute__((ext_vector_type(8))) __bf16 bf16x8;
typedef __attribute__((ext_vector_type(4))) float f32x4;

#define NROW 8192
#define DMODEL 256
#define HD 64
#define LDT 72   // LDS row stride (u16): 144 B = 9*16B aligned

__device__ __forceinline__ u16 f2bf(float f) {   // RNE f32 -> bf16
    u32 u = __builtin_bit_cast(u32, f);
    u += 0x7FFFu + ((u >> 16) & 1u);
    return (u16)(u >> 16);
}
__device__ __forceinline__ bf16x8 ldb8(const u16* p) {
    uint4 v = *(const uint4*)p;
    return __builtin_bit_cast(bf16x8, v);
}
__device__ __forceinline__ f32x4 mfma16(bf16x8 a, bf16x8 b, f32x4 c) {
    return __builtin_amdgcn_mfma_f32_16x16x32_bf16(a, b, c, 0, 0, 0);
}

// ---------------- kernel P: x f32->bf16 ; W f32->bf16 transposed -----------
__global__ __launch_bounds__(256) void k_prep(
    const float* __restrict__ x,
    const float* __restrict__ Wq, const float* __restrict__ Wk,
    const float* __restrict__ Wv,
    u16* __restrict__ xb, u16* __restrict__ Wt) {
    const int t = threadIdx.x;
    if (blockIdx.x < 1024) {                       // x convert: 8 elems/thread
        size_t idx = (size_t)blockIdx.x * 2048 + t * 8;
        f32x4 a = *(const f32x4*)&x[idx];
        f32x4 b = *(const f32x4*)&x[idx + 4];
        uint4 o;
        o.x = (u32)f2bf(a[0]) | ((u32)f2bf(a[1]) << 16);
        o.y = (u32)f2bf(a[2]) | ((u32)f2bf(a[3]) << 16);
        o.z = (u32)f2bf(b[0]) | ((u32)f2bf(b[1]) << 16);
        o.w = (u32)f2bf(b[2]) | ((u32)f2bf(b[3]) << 16);
        *(uint4*)&xb[idx] = o;
        return;
    }
    // W transpose: 48 blocks, 64x64 tiles
    __shared__ __align__(16) u16 lw[64 * LDT];
    int wb = blockIdx.x - 1024;
    int mat = wb >> 4, tile = wb & 15;
    int k0 = (tile >> 2) * 64, n0 = (tile & 3) * 64;
    const float* W = (mat == 0) ? Wq : ((mat == 1) ? Wk : Wv);
    #pragma unroll
    for (int i = 0; i < 4; ++i) {
        int c = t + 256 * i;
        int k = c >> 4, c4 = c & 15;
        f32x4 w4 = *(const f32x4*)&W[(size_t)(k0 + k) * DMODEL + n0 + c4 * 4];
        uint2 pk;
        pk.x = (u32)f2bf(w4[0]) | ((u32)f2bf(w4[1]) << 16);
        pk.y = (u32)f2bf(w4[2]) | ((u32)f2bf(w4[3]) << 16);
        *(uint2*)&lw[k * LDT + c4 * 4] = pk;
    }
    __syncthreads();
    #pragma unroll
    for (int i = 0; i < 2; ++i) {
        int c = t + 256 * i;
        int n = c >> 3, k8 = c & 7;
        union { uint4 u; u16 s[8]; } pk;
        #pragma unroll
        for (int j = 0; j < 8; ++j) pk.s[j] = lw[(k8 * 8 + j) * LDT + n];
        *(uint4*)&Wt[(size_t)mat * 65536 + (size_t)(n0 + n) * DMODEL + k0 + k8 * 8] = pk.u;
    }
}

// ---------------- kernel 0: edge (256MB int32) -> transposed bitmask (8MB) ---
// bits[nw*8192 + m]: bit i = (edge[m][nw*64+i] != 0). One wave per row m.
__global__ __launch_bounds__(256, 4) void k_bitmask(const int* __restrict__ edge,
                                                    u64* __restrict__ bits) {
    const int lane = threadIdx.x & 63;
    const int wv = threadIdx.x >> 6;
    const u32 m = blockIdx.x * 4u + (u32)wv;       // row
    const size_t rbase = (size_t)m * NROW;
    for (int cc = 0; cc < 32; cc += 4) {           // 16 loads (4 KB) in flight
        int v[16];
        #pragma unroll
        for (int j = 0; j < 16; ++j) v[j] = edge[rbase + cc * 256 + j * 64 + lane];
        u64 b[16];
        #pragma unroll
        for (int j = 0; j < 16; ++j) b[j] = __ballot(v[j] != 0);
        if (lane == 0) {
            #pragma unroll
            for (int j = 0; j < 16; ++j) bits[(size_t)(cc * 4 + j) * NROW + m] = b[j];
        }
    }
}

// ---------------- kernel 1: QKV projections (bf16 in -> bf16 out) ----------
// blockIdx.y: 0-3 -> Q (scaled by 0.125*log2e), 4-7 -> K, 8-11 -> V (transposed)
__global__ __launch_bounds__(256, 3) void k_qkv(
    const u16* __restrict__ xb, const u16* __restrict__ Wt,
    const float* __restrict__ bq, const float* __restrict__ bk,
    const float* __restrict__ bv,
    u16* __restrict__ Qo, u16* __restrict__ Ko, u16* __restrict__ Vt) {
    __shared__ __align__(16) u16 ax[128 * LDT];
    __shared__ __align__(16) u16 wt[64 * LDT];
    const int t = threadIdx.x;
    const int lane = t & 63, wv = t >> 6;
    const int q4 = lane >> 4, l15 = lane & 15;
    const int wr = wv >> 1, wc = wv & 1;
    const int row0 = blockIdx.x * 128;
    const int mat = blockIdx.y >> 2;
    const int c0 = (blockIdx.y & 3) * 64;
    const u16* Wm = Wt + (size_t)mat * 65536;
    const float* bias = (mat == 0) ? bq : ((mat == 1) ? bk : bv);

    f32x4 acc[8];
    #pragma unroll
    for (int i = 0; i < 8; ++i) acc[i] = {0.f, 0.f, 0.f, 0.f};

    for (int kk = 0; kk < DMODEL; kk += 64) {
        #pragma unroll
        for (int i = 0; i < 4; ++i) {              // stage x tile 128x64
            int c = t + 256 * i;
            int row = c >> 3, c8 = c & 7;
            *(uint4*)&ax[row * LDT + c8 * 8] =
                *(const uint4*)&xb[(size_t)(row0 + row) * DMODEL + kk + c8 * 8];
        }
        #pragma unroll
        for (int i = 0; i < 2; ++i) {              // stage Wt tile 64(n)x64(k)
            int c = t + 256 * i;
            int n = c >> 3, c8 = c & 7;
            *(uint4*)&wt[n * LDT + c8 * 8] =
                *(const uint4*)&Wm[(size_t)(c0 + n) * DMODEL + kk + c8 * 8];
        }
        __syncthreads();
        #pragma unroll
        for (int ks = 0; ks < 2; ++ks) {
            bf16x8 xf[4], wf[2];
            #pragma unroll
            for (int it = 0; it < 4; ++it)
                xf[it] = ldb8(&ax[(wr * 64 + it * 16 + l15) * LDT + ks * 32 + q4 * 8]);
            #pragma unroll
            for (int jt = 0; jt < 2; ++jt)
                wf[jt] = ldb8(&wt[(wc * 32 + jt * 16 + l15) * LDT + ks * 32 + q4 * 8]);
            if (mat < 2) {
                #pragma unroll
                for (int it = 0; it < 4; ++it)
                    #pragma unroll
                    for (int jt = 0; jt < 2; ++jt)
                        acc[it * 2 + jt] = mfma16(xf[it], wf[jt], acc[it * 2 + jt]);
            } else {  // V: swapped operands -> D = (xW)^T
                #pragma unroll
                for (int jt = 0; jt < 2; ++jt)
                    #pragma unroll
                    for (int it = 0; it < 4; ++it)
                        acc[jt * 4 + it] = mfma16(wf[jt], xf[it], acc[jt * 4 + it]);
            }
        }
        __syncthreads();
    }

    if (mat < 2) {
        u16* out = (mat == 0) ? Qo : Ko;
        const float scale = (mat == 0) ? 0.18033688f : 1.0f;  // 0.125*log2(e)
        #pragma unroll
        for (int jt = 0; jt < 2; ++jt) {
            int col = c0 + wc * 32 + jt * 16 + l15;
            float bcol = bias[col];
            #pragma unroll
            for (int it = 0; it < 4; ++it) {
                int rowb = row0 + wr * 64 + it * 16 + q4 * 4;
                f32x4 a = acc[it * 2 + jt];
                #pragma unroll
                for (int r = 0; r < 4; ++r)
                    out[(size_t)(rowb + r) * DMODEL + col] = f2bf((a[r] + bcol) * scale);
            }
        }
    } else {
        #pragma unroll
        for (int jt = 0; jt < 2; ++jt) {
            #pragma unroll
            for (int r = 0; r < 4; ++r) {
                int drow = c0 + wc * 32 + jt * 16 + q4 * 4 + r;
                float bd = bias[drow];
                #pragma unroll
                for (int it = 0; it < 4; ++it) {
                    int col = row0 + wr * 64 + it * 16 + l15;
                    Vt[(size_t)drow * NROW + col] = f2bf(acc[jt * 4 + it][r] + bd);
                }
            }
        }
    }
}

// ---------------- kernel 2: flash attention, m-partitioned waves -----------
// grid 512: h=(bid>>1)&3, qt=((bid>>3)<<1)|(bid&1); block = 64 Q-rows (n0..n0+63).
// BN=128 per iter; wave w owns m-slice [w*32, w*32+32). All 64 Q-rows' fragments
// live in registers (identical across waves). S^T = K Qt (rows m, cols n);
// P^T through per-wave LDS (stride-40 = bank-conflict-free); O^T = Vt P^T partial
// per wave, cross-wave reduced in LDS epilogue. l via ones-MFMA.
__global__ __launch_bounds__(256, 2) void k_attn(
    const u16* __restrict__ Q, const u16* __restrict__ K,
    const u16* __restrict__ Vt, const u64* __restrict__ bits,
    float* __restrict__ out) {
    __shared__ __align__(16) u16 sK[128 * LDT];    // K tile: 128 m x 64 d
    __shared__ __align__(16) u16 sV[64 * 136];     // V^T tile: 64 d x 128 m
    __shared__ __align__(16) u16 sP[4][64 * 40];   // per-wave P^T: 64 n x 32 m
    __shared__ __align__(16) u32 sB[2][128];       // mask lo/hi words per m

    const int t = threadIdx.x;
    const int lane = t & 63, w = t >> 6;
    const int q4 = lane >> 4, l15 = lane & 15;
    const int bid = blockIdx.x;
    const int h = (bid >> 1) & 3;
    const int qt = ((bid >> 3) << 1) | (bid & 1);
    const int n0 = qt * 64;
    u16* sPw = &sP[w][0];

    // Q fragments: all 64 rows x 64 d, in registers (32 VGPRs)
    bf16x8 qf[4][2];
    #pragma unroll
    for (int nt = 0; nt < 4; ++nt)
        #pragma unroll
        for (int ks = 0; ks < 2; ++ks)
            qf[nt][ks] = ldb8(&Q[(size_t)(n0 + nt * 16 + l15) * DMODEL + h * HD + ks * 32 + q4 * 8]);

    uint4 onesu = {0x3F803F80u, 0x3F803F80u, 0x3F803F80u, 0x3F803F80u};
    const bf16x8 ones = __builtin_bit_cast(bf16x8, onesu);

    f32x4 o[4][4];          // O^T partial: [d-tile][n-tile], d=dt*16+q4*4+r, n=nt*16+l15
    f32x4 lacc[4];
    #pragma unroll
    for (int nt = 0; nt < 4; ++nt) {
        lacc[nt] = {0.f, 0.f, 0.f, 0.f};
        #pragma unroll
        for (int dt = 0; dt < 4; ++dt) o[dt][nt] = {0.f, 0.f, 0.f, 0.f};
    }

    // staging coords
    const int krow = t >> 3, kc8 = (t & 7) * 8;    // K: +32 rows per i
    const int vrow = t >> 4, vc16 = (t & 15) * 8;  // V: +16 rows per i

    uint4 rk[4], rv[4]; uint2 rb;
    #pragma unroll
    for (int i = 0; i < 4; ++i) {
        rk[i] = *(const uint4*)&K[(size_t)(i * 32 + krow) * DMODEL + h * HD + kc8];
        rv[i] = *(const uint4*)&Vt[(size_t)(h * HD + i * 16 + vrow) * NROW + vc16];
    }
    if (t < 128) rb = *(const uint2*)&bits[(size_t)qt * NROW + t];

    for (int kt = 0; kt < 64; ++kt) {
        // commit prefetched tile
        #pragma unroll
        for (int i = 0; i < 4; ++i) {
            *(uint4*)&sK[(i * 32 + krow) * LDT + kc8] = rk[i];
            *(uint4*)&sV[(i * 16 + vrow) * 136 + vc16] = rv[i];
        }
        if (t < 128) { sB[0][t] = rb.x; sB[1][t] = rb.y; }
        __syncthreads();

        if (kt < 63) {                             // prefetch next tile (in flight)
            int m0n = (kt + 1) * 128;
            #pragma unroll
            for (int i = 0; i < 4; ++i) {
                rk[i] = *(const uint4*)&K[(size_t)(m0n + i * 32 + krow) * DMODEL + h * HD + kc8];
                rv[i] = *(const uint4*)&Vt[(size_t)(h * HD + i * 16 + vrow) * NROW + m0n + vc16];
            }
            if (t < 128) rb = *(const uint2*)&bits[(size_t)qt * NROW + m0n + t];
        }

        // S^T = K Q^T over wave's 32 m
        f32x4 s[2][4];
        #pragma unroll
        for (int tjm = 0; tjm < 2; ++tjm) {
            #pragma unroll
            for (int nt = 0; nt < 4; ++nt) s[tjm][nt] = {0.f, 0.f, 0.f, 0.f};
            #pragma unroll
            for (int ks = 0; ks < 2; ++ks) {
                bf16x8 kb = ldb8(&sK[(w * 32 + tjm * 16 + l15) * LDT + ks * 32 + q4 * 8]);
                #pragma unroll
                for (int nt = 0; nt < 4; ++nt)
                    s[tjm][nt] = mfma16(kb, qf[nt][ks], s[tjm][nt]);
            }
        }

        // mask + exp2 + pack P^T -> per-wave LDS (conflict-free stride 40)
        #pragma unroll
        for (int tjm = 0; tjm < 2; ++tjm) {
            #pragma unroll
            for (int nt = 0; nt < 4; ++nt) {
                uint4 bw = *(const uint4*)&sB[nt >> 1][w * 32 + tjm * 16 + q4 * 4];
                u32 wd[4] = {bw.x, bw.y, bw.z, bw.w};
                const u32 shift = (u32)((nt & 1) * 16 + l15);
                u32 ub[4];
                #pragma unroll
                for (int r = 0; r < 4; ++r) {
                    float sv = ((wd[r] >> shift) & 1u) ? s[tjm][nt][r] : -1e30f;
                    ub[r] = __builtin_bit_cast(u32, __builtin_amdgcn_exp2f(sv));
                }
                uint2 pk;
                pk.x = (ub[0] >> 16) | (ub[1] & 0xFFFF0000u);
                pk.y = (ub[2] >> 16) | (ub[3] & 0xFFFF0000u);
                *(uint2*)&sPw[(nt * 16 + l15) * 40 + tjm * 16 + q4 * 4] = pk;
            }
        }
        asm volatile("s_waitcnt lgkmcnt(0)" ::: "memory");  // sPw is wave-private

        // O^T += Vt P^T ; l += ones P^T   (k = wave's 32 m)
        bf16x8 pf[4];
        #pragma unroll
        for (int nt = 0; nt < 4; ++nt)
            pf[nt] = ldb8(&sPw[(nt * 16 + l15) * 40 + q4 * 8]);
        #pragma unroll
        for (int dt = 0; dt < 4; ++dt) {
            bf16x8 vb = ldb8(&sV[(dt * 16 + l15) * 136 + w * 32 + q4 * 8]);
            #pragma unroll
            for (int nt = 0; nt < 4; ++nt)
                o[dt][nt] = mfma16(vb, pf[nt], o[dt][nt]);
        }
        #pragma unroll
        for (int nt = 0; nt < 4; ++nt)
            lacc[nt] = mfma16(ones, pf[nt], lacc[nt]);
        __syncthreads();
    }

    // ---- epilogue: cross-wave reduce O^T and l, normalize, store ----
    float* S = (float*)sK;                         // S'[n][d]: 65 x 68 f32 (17.7 KB)
    #pragma unroll 1
    for (int p = 0; p < 4; ++p) {
        if (w == p) {
            #pragma unroll
            for (int nt = 0; nt < 4; ++nt) {
                #pragma unroll
                for (int dt = 0; dt < 4; ++dt) {
                    f32x4* dst = (f32x4*)&S[(nt * 16 + l15) * 68 + dt * 16 + q4 * 4];
                    *dst = (p == 0) ? o[dt][nt] : (*dst + o[dt][nt]);
                }
                if (q4 == 0) {
                    float* lp = &S[64 * 68 + nt * 16 + l15];
                    *lp = (p == 0) ? lacc[nt][0] : (*lp + lacc[nt][0]);
                }
            }
        }
        __syncthreads();
    }
    #pragma unroll
    for (int j = 0; j < 4; ++j) {
        int n = j * 16 + (t >> 4);
        int d0 = (t & 15) * 4;
        float inv = __builtin_amdgcn_rcpf(S[64 * 68 + n] + 1e-30f);
        f32x4 v = *(f32x4*)&S[n * 68 + d0];
        v = v * inv;
        *(f32x4*)&out[(size_t)(n0 + n) * DMODEL + h * HD + d0] = v;
    }
}

extern "C" void kernel_launch(void* const* d_in, const int* in_sizes, int n_in,
                              void* d_out, int out_size, void* d_ws, size_t ws_size,
                              hipStream_t stream) {
    const float* x  = (const float*)d_in[0];
    const int* edge = (const int*)d_in[1];
    const float* Wq = (const float*)d_in[2];
    const float* bq = (const float*)d_in[3];
    const float* Wk = (const float*)d_in[4];
    const float* bk = (const float*)d_in[5];
    const float* Wv = (const float*)d_in[6];
    const float* bv = (const float*)d_in[7];

    char* ws = (char*)d_ws;
    u64* bits = (u64*)ws;                        //  8 MB
    u16* Qo  = (u16*)(ws + (8u << 20));          //  4 MB (bf16, Q pre-scaled)
    u16* Ko  = (u16*)(ws + (12u << 20));         //  4 MB (bf16)
    u16* Vt  = (u16*)(ws + (16u << 20));         //  4 MB (bf16, [256][8192])
    u16* xb  = (u16*)(ws + (20u << 20));         //  4 MB (bf16 x)
    u16* Wt  = (u16*)(ws + (24u << 20));         //  384 KB (bf16, 3x[256n][256k])
    float* out = (float*)d_out;

    hipLaunchKernelGGL(k_prep, dim3(1072), dim3(256), 0, stream, x, Wq, Wk, Wv, xb, Wt);
    hipLaunchKernelGGL(k_bitmask, dim3(2048), dim3(256), 0, stream, edge, bits);
    hipLaunchKernelGGL(k_qkv, dim3(64, 12), dim3(256), 0, stream,
                       xb, Wt, bq, bk, bv, Qo, Ko, Vt);
    hipLaunchKernelGGL(k_attn, dim3(512), dim3(256), 0, stream, Qo, Ko, Vt, bits, out);
}